// Round 1
// baseline (497.300 us; speedup 1.0000x reference)
//
#include <hip/hip_runtime.h>
#include <hip/hip_bf16.h>

// GCN: 4 layers, N=50000 nodes, E=800000 edges, C: 128->96->96->96->96
// Strategy: build CSR (sorted-by-dst edge list) once per launch, then per layer:
//   fp32 tiled GEMM (h = x@W)  ->  node-parallel gather-aggregate (+self loop,
//   bias, relu) with zero fp32 atomics.

#define NN 50000
#define NE 800000
#define CIN0 128
#define CH 96

static inline size_t al256(size_t x) { return (x + 255) & ~size_t(255); }

// ---------------- graph preprocessing ----------------

__global__ void zero_cnt_k(int* __restrict__ cnt, int n) {
    int i = blockIdx.x * blockDim.x + threadIdx.x;
    if (i < n) cnt[i] = 0;
}

__global__ void count_deg_k(const int* __restrict__ dst, int* __restrict__ cnt, int e) {
    int i = blockIdx.x * blockDim.x + threadIdx.x;
    if (i < e) atomicAdd(&cnt[dst[i]], 1);
}

// block-local exclusive scan (256 elems/block); bsum gets block totals
__global__ void scan1_k(const int* __restrict__ cnt, int* __restrict__ offs,
                        int* __restrict__ bsum, int n) {
    __shared__ int s[256];
    int tid = threadIdx.x;
    int i = blockIdx.x * 256 + tid;
    int v = (i < n) ? cnt[i] : 0;
    s[tid] = v;
    __syncthreads();
    for (int d = 1; d < 256; d <<= 1) {
        int t = (tid >= d) ? s[tid - d] : 0;
        __syncthreads();
        s[tid] += t;
        __syncthreads();
    }
    if (i <= n) offs[i] = s[tid] - v;          // exclusive within block
    if (tid == 255) bsum[blockIdx.x] = s[255]; // block total
}

// single-block exclusive scan of block sums (nb <= 256)
__global__ void scan2_k(const int* __restrict__ bsum, int* __restrict__ boff, int nb) {
    __shared__ int s[256];
    int t = threadIdx.x;
    int v = (t < nb) ? bsum[t] : 0;
    s[t] = v;
    __syncthreads();
    for (int d = 1; d < 256; d <<= 1) {
        int u = (t >= d) ? s[t - d] : 0;
        __syncthreads();
        s[t] += u;
        __syncthreads();
    }
    if (t < nb) boff[t] = s[t] - v;
}

// add block offsets; also init cursor copy and dinv = rsqrt(deg+1)
__global__ void scan3_k(int* __restrict__ offs, const int* __restrict__ boff,
                        int* __restrict__ cursor, float* __restrict__ dinv,
                        const int* __restrict__ cnt, int n) {
    int i = blockIdx.x * 256 + threadIdx.x;
    if (i <= n) {
        int o = offs[i] + boff[blockIdx.x];
        offs[i] = o;
        if (i < n) {
            cursor[i] = o;
            dinv[i] = rsqrtf(1.0f + (float)cnt[i]);
        }
    }
}

// counting-sort scatter: edge e -> slot p in dst-sorted order; store src + norm
__global__ void scatter_k(const int* __restrict__ src, const int* __restrict__ dst,
                          const float* __restrict__ dinv, int* __restrict__ cursor,
                          int* __restrict__ es, float* __restrict__ en, int e) {
    int i = blockIdx.x * blockDim.x + threadIdx.x;
    if (i < e) {
        int s = src[i], d = dst[i];
        int p = atomicAdd(&cursor[d], 1);
        es[p] = s;
        en[p] = dinv[s] * dinv[d];
    }
}

// ---------------- dense GEMM: H[n x 96] = X[n x CIN] @ W[CIN x 96] ----------------
// block = 192 threads, tile = 32 rows x 96 cols. thread = (c4 = tid%24 -> 4 cols,
// rr = tid/24 -> 4 rows). W and X tile staged in LDS; float4 throughout.
template <int CIN, int XPAD>
__global__ __launch_bounds__(192) void gemm_k(const float* __restrict__ X,
                                              const float* __restrict__ W,
                                              float* __restrict__ H, int n) {
    __shared__ float ws[CIN][CH];
    __shared__ float xs[32][CIN + XPAD];
    int tid = threadIdx.x;
    int c4 = tid % 24;
    int rr = tid / 24;  // 0..7
    int row0 = blockIdx.x * 32;

    // stage W (CIN*24 float4)
    {
        const float4* Wv = (const float4*)W;
        float4* wv = (float4*)&ws[0][0];
        for (int i = tid; i < CIN * 24; i += 192) wv[i] = Wv[i];
    }
    // stage X tile (32 x CIN), zero-pad tail rows
    for (int i = tid; i < 32 * (CIN / 4); i += 192) {
        int r = i / (CIN / 4), k = i % (CIN / 4);
        int gr = row0 + r;
        float4 v = {0.f, 0.f, 0.f, 0.f};
        if (gr < n) v = *(const float4*)&X[(size_t)gr * CIN + k * 4];
        *(float4*)&xs[r][k * 4] = v;
    }
    __syncthreads();

    float4 acc[4];
#pragma unroll
    for (int i = 0; i < 4; i++) acc[i] = {0.f, 0.f, 0.f, 0.f};

    for (int k4 = 0; k4 < CIN / 4; k4++) {
        float4 w0 = *(const float4*)&ws[4 * k4 + 0][c4 * 4];
        float4 w1 = *(const float4*)&ws[4 * k4 + 1][c4 * 4];
        float4 w2 = *(const float4*)&ws[4 * k4 + 2][c4 * 4];
        float4 w3 = *(const float4*)&ws[4 * k4 + 3][c4 * 4];
#pragma unroll
        for (int i = 0; i < 4; i++) {
            float4 xv = *(const float4*)&xs[rr * 4 + i][k4 * 4];
            acc[i].x = fmaf(xv.x, w0.x, fmaf(xv.y, w1.x, fmaf(xv.z, w2.x, fmaf(xv.w, w3.x, acc[i].x))));
            acc[i].y = fmaf(xv.x, w0.y, fmaf(xv.y, w1.y, fmaf(xv.z, w2.y, fmaf(xv.w, w3.y, acc[i].y))));
            acc[i].z = fmaf(xv.x, w0.z, fmaf(xv.y, w1.z, fmaf(xv.z, w2.z, fmaf(xv.w, w3.z, acc[i].z))));
            acc[i].w = fmaf(xv.x, w0.w, fmaf(xv.y, w1.w, fmaf(xv.z, w2.w, fmaf(xv.w, w3.w, acc[i].w))));
        }
    }
#pragma unroll
    for (int i = 0; i < 4; i++) {
        int gr = row0 + rr * 4 + i;
        if (gr < n) *(float4*)&H[(size_t)gr * CH + c4 * 4] = acc[i];
    }
}

// ---------------- aggregation: OUT[n] = sum_{e in CSR(n)} norm_e * H[src_e]
//                  + dinv[n]^2 * H[n] + b  (optional relu) ----------------
// 24 threads (one float4 lane each) per node; block 192 = 8 nodes.
__global__ __launch_bounds__(192) void agg_k(const float* __restrict__ H,
                                             const int* __restrict__ offs,
                                             const int* __restrict__ es,
                                             const float* __restrict__ en,
                                             const float* __restrict__ dinv,
                                             const float* __restrict__ b,
                                             float* __restrict__ OUT, int n, int do_relu) {
    int tid = threadIdx.x;
    int g = tid / 24, c4 = tid % 24;
    int node = blockIdx.x * 8 + g;
    if (node >= n) return;
    int e0 = offs[node], e1 = offs[node + 1];
    float ax = 0.f, ay = 0.f, az = 0.f, aw = 0.f;
    for (int e = e0; e < e1; e++) {
        int s = es[e];
        float w = en[e];
        float4 hv = *(const float4*)&H[(size_t)s * CH + c4 * 4];
        ax = fmaf(w, hv.x, ax);
        ay = fmaf(w, hv.y, ay);
        az = fmaf(w, hv.z, az);
        aw = fmaf(w, hv.w, aw);
    }
    float di = dinv[node];
    float sw = di * di;
    float4 hv = *(const float4*)&H[(size_t)node * CH + c4 * 4];
    float4 bv = *(const float4*)&b[c4 * 4];
    ax = fmaf(sw, hv.x, ax) + bv.x;
    ay = fmaf(sw, hv.y, ay) + bv.y;
    az = fmaf(sw, hv.z, az) + bv.z;
    aw = fmaf(sw, hv.w, aw) + bv.w;
    if (do_relu) {
        ax = fmaxf(ax, 0.f);
        ay = fmaxf(ay, 0.f);
        az = fmaxf(az, 0.f);
        aw = fmaxf(aw, 0.f);
    }
    float4 o = {ax, ay, az, aw};
    *(float4*)&OUT[(size_t)node * CH + c4 * 4] = o;
}

// ---------------- launch ----------------

extern "C" void kernel_launch(void* const* d_in, const int* in_sizes, int n_in,
                              void* d_out, int out_size, void* d_ws, size_t ws_size,
                              hipStream_t stream) {
    const float* x = (const float*)d_in[0];
    const int* ei = (const int*)d_in[1];  // [2, E]: row0 = src, row1 = dst
    const float* W1 = (const float*)d_in[2];
    const float* b1 = (const float*)d_in[3];
    const float* W2 = (const float*)d_in[4];
    const float* b2 = (const float*)d_in[5];
    const float* W3 = (const float*)d_in[6];
    const float* b3 = (const float*)d_in[7];
    const float* W4 = (const float*)d_in[8];
    const float* b4 = (const float*)d_in[9];
    float* out = (float*)d_out;

    const int* src = ei;
    const int* dst = ei + NE;

    char* ws = (char*)d_ws;
    size_t o = 0;
    float* H = (float*)(ws + o);      o += al256((size_t)NN * CH * 4);
    float* F = (float*)(ws + o);      o += al256((size_t)NN * CH * 4);
    int* cnt = (int*)(ws + o);        o += al256((size_t)NN * 4);
    int* offs = (int*)(ws + o);       o += al256((size_t)(NN + 1) * 4);
    int* cursor = (int*)(ws + o);     o += al256((size_t)NN * 4);
    float* dinv = (float*)(ws + o);   o += al256((size_t)NN * 4);
    int* es = (int*)(ws + o);         o += al256((size_t)NE * 4);
    float* en = (float*)(ws + o);     o += al256((size_t)NE * 4);
    int* bsum = (int*)(ws + o);       o += al256(256 * 4);
    int* boff = (int*)(ws + o);       o += al256(256 * 4);

    const int NB_NODE = (NN + 255) / 256;          // 196
    const int NB_EDGE = (NE + 255) / 256;          // 3125
    const int NB_SCAN = (NN + 1 + 255) / 256;      // 196 (covers i<=N)
    const int NB_GEMM = (NN + 31) / 32;            // 1563
    const int NB_AGG = (NN + 7) / 8;               // 6250

    // graph preprocessing (once per launch)
    zero_cnt_k<<<NB_NODE, 256, 0, stream>>>(cnt, NN);
    count_deg_k<<<NB_EDGE, 256, 0, stream>>>(dst, cnt, NE);
    scan1_k<<<NB_SCAN, 256, 0, stream>>>(cnt, offs, bsum, NN);
    scan2_k<<<1, 256, 0, stream>>>(bsum, boff, NB_SCAN);
    scan3_k<<<NB_SCAN, 256, 0, stream>>>(offs, boff, cursor, dinv, cnt, NN);
    scatter_k<<<NB_EDGE, 256, 0, stream>>>(src, dst, dinv, cursor, es, en, NE);

    // layer 1: x(128) -> F(96)
    gemm_k<CIN0, 0><<<NB_GEMM, 192, 0, stream>>>(x, W1, H, NN);   // 64KB LDS exactly
    agg_k<<<NB_AGG, 192, 0, stream>>>(H, offs, es, en, dinv, b1, F, NN, 1);
    // layer 2: F -> F
    gemm_k<CH, 4><<<NB_GEMM, 192, 0, stream>>>(F, W2, H, NN);
    agg_k<<<NB_AGG, 192, 0, stream>>>(H, offs, es, en, dinv, b2, F, NN, 1);
    // layer 3
    gemm_k<CH, 4><<<NB_GEMM, 192, 0, stream>>>(F, W3, H, NN);
    agg_k<<<NB_AGG, 192, 0, stream>>>(H, offs, es, en, dinv, b3, F, NN, 1);
    // layer 4 (no relu) -> d_out
    gemm_k<CH, 4><<<NB_GEMM, 192, 0, stream>>>(F, W4, H, NN);
    agg_k<<<NB_AGG, 192, 0, stream>>>(H, offs, es, en, dinv, b4, out, NN, 0);
}

// Round 2
// 446.986 us; speedup vs baseline: 1.1126x; 1.1126x over previous
//
#include <hip/hip_runtime.h>
#include <hip/hip_bf16.h>
#include <hip/hip_fp16.h>

// GCN: 4 layers, N=50000 nodes, E=800000 edges, C: 128->96->96->96->96
// CSR-by-dst counting sort once per launch; per layer: fp32 GEMM (fp16 output
// store) -> node-parallel gather-aggregate (fp16 gathers, fp32 accumulate).

#define NN 50000
#define NE 800000
#define CIN0 128
#define CH 96

static inline size_t al256(size_t x) { return (x + 255) & ~size_t(255); }

// ---------------- graph preprocessing ----------------

__global__ void count_deg_k(const int* __restrict__ dst, int* __restrict__ cnt, int e) {
    int i = blockIdx.x * blockDim.x + threadIdx.x;
    if (i < e) atomicAdd(&cnt[dst[i]], 1);
}

// block-local exclusive scan (256 elems/block); bsum gets block totals
__global__ void scan1_k(const int* __restrict__ cnt, int* __restrict__ offs,
                        int* __restrict__ bsum, int n) {
    __shared__ int s[256];
    int tid = threadIdx.x;
    int i = blockIdx.x * 256 + tid;
    int v = (i < n) ? cnt[i] : 0;
    s[tid] = v;
    __syncthreads();
    for (int d = 1; d < 256; d <<= 1) {
        int t = (tid >= d) ? s[tid - d] : 0;
        __syncthreads();
        s[tid] += t;
        __syncthreads();
    }
    if (i <= n) offs[i] = s[tid] - v;          // exclusive within block
    if (tid == 255) bsum[blockIdx.x] = s[255]; // block total
}

// single-block exclusive scan of block sums (nb <= 256)
__global__ void scan2_k(const int* __restrict__ bsum, int* __restrict__ boff, int nb) {
    __shared__ int s[256];
    int t = threadIdx.x;
    int v = (t < nb) ? bsum[t] : 0;
    s[t] = v;
    __syncthreads();
    for (int d = 1; d < 256; d <<= 1) {
        int u = (t >= d) ? s[t - d] : 0;
        __syncthreads();
        s[t] += u;
        __syncthreads();
    }
    if (t < nb) boff[t] = s[t] - v;
}

// add block offsets; also init cursor copy and dinv = rsqrt(deg+1)
__global__ void scan3_k(int* __restrict__ offs, const int* __restrict__ boff,
                        int* __restrict__ cursor, float* __restrict__ dinv,
                        const int* __restrict__ cnt, int n) {
    int i = blockIdx.x * 256 + threadIdx.x;
    if (i <= n) {
        int o = offs[i] + boff[blockIdx.x];
        offs[i] = o;
        if (i < n) {
            cursor[i] = o;
            dinv[i] = rsqrtf(1.0f + (float)cnt[i]);
        }
    }
}

// counting-sort scatter: edge e -> slot p in dst-sorted order; store src only
// (norm recomputed in agg from dinv — halves the random write traffic).
__global__ void scatter_k(const int* __restrict__ src, const int* __restrict__ dst,
                          int* __restrict__ cursor, int* __restrict__ es, int e) {
    int i = blockIdx.x * blockDim.x + threadIdx.x;
    if (i < e) {
        int s = src[i], d = dst[i];
        int p = atomicAdd(&cursor[d], 1);
        es[p] = s;
    }
}

// ---------------- dense GEMM: Hh[n x 96](fp16) = X[n x CIN](fp32) @ W[CIN x 96] ----
// block = 192 threads, tile = 32 rows x 96 cols. fp32 compute, fp16 store.
template <int CIN, int XPAD>
__global__ __launch_bounds__(192) void gemm_k(const float* __restrict__ X,
                                              const float* __restrict__ W,
                                              __half* __restrict__ Hh, int n) {
    __shared__ float ws[CIN][CH];
    __shared__ float xs[32][CIN + XPAD];
    int tid = threadIdx.x;
    int c4 = tid % 24;
    int rr = tid / 24;  // 0..7
    int row0 = blockIdx.x * 32;

    // stage W (CIN*24 float4)
    {
        const float4* Wv = (const float4*)W;
        float4* wv = (float4*)&ws[0][0];
        for (int i = tid; i < CIN * 24; i += 192) wv[i] = Wv[i];
    }
    // stage X tile (32 x CIN), zero-pad tail rows
    for (int i = tid; i < 32 * (CIN / 4); i += 192) {
        int r = i / (CIN / 4), k = i % (CIN / 4);
        int gr = row0 + r;
        float4 v = {0.f, 0.f, 0.f, 0.f};
        if (gr < n) v = *(const float4*)&X[(size_t)gr * CIN + k * 4];
        *(float4*)&xs[r][k * 4] = v;
    }
    __syncthreads();

    float4 acc[4];
#pragma unroll
    for (int i = 0; i < 4; i++) acc[i] = {0.f, 0.f, 0.f, 0.f};

    for (int k4 = 0; k4 < CIN / 4; k4++) {
        float4 w0 = *(const float4*)&ws[4 * k4 + 0][c4 * 4];
        float4 w1 = *(const float4*)&ws[4 * k4 + 1][c4 * 4];
        float4 w2 = *(const float4*)&ws[4 * k4 + 2][c4 * 4];
        float4 w3 = *(const float4*)&ws[4 * k4 + 3][c4 * 4];
#pragma unroll
        for (int i = 0; i < 4; i++) {
            float4 xv = *(const float4*)&xs[rr * 4 + i][k4 * 4];
            acc[i].x = fmaf(xv.x, w0.x, fmaf(xv.y, w1.x, fmaf(xv.z, w2.x, fmaf(xv.w, w3.x, acc[i].x))));
            acc[i].y = fmaf(xv.x, w0.y, fmaf(xv.y, w1.y, fmaf(xv.z, w2.y, fmaf(xv.w, w3.y, acc[i].y))));
            acc[i].z = fmaf(xv.x, w0.z, fmaf(xv.y, w1.z, fmaf(xv.z, w2.z, fmaf(xv.w, w3.z, acc[i].z))));
            acc[i].w = fmaf(xv.x, w0.w, fmaf(xv.y, w1.w, fmaf(xv.z, w2.w, fmaf(xv.w, w3.w, acc[i].w))));
        }
    }
#pragma unroll
    for (int i = 0; i < 4; i++) {
        int gr = row0 + rr * 4 + i;
        if (gr < n) {
            __half2 p01 = __floats2half2_rn(acc[i].x, acc[i].y);
            __half2 p23 = __floats2half2_rn(acc[i].z, acc[i].w);
            uint2 u;
            u.x = *(unsigned int*)&p01;
            u.y = *(unsigned int*)&p23;
            *(uint2*)&Hh[(size_t)gr * CH + c4 * 4] = u;
        }
    }
}

// ---------------- aggregation (fp16 gathers, fp32 accumulate) ----------------
// OUT[n] = sum_{e in CSR(n)} dinv[src]*dinv[n] * Hh[src] + dinv[n]^2*Hh[n] + b
// 24 threads (one 4-half chunk each) per node; block 192 = 8 nodes.
__device__ __forceinline__ void acc_half4(unsigned int lo, unsigned int hi, float w,
                                          float& ax, float& ay, float& az, float& aw) {
    __half2 h01 = *(__half2*)&lo;
    __half2 h23 = *(__half2*)&hi;
    float2 f01 = __half22float2(h01);
    float2 f23 = __half22float2(h23);
    ax = fmaf(w, f01.x, ax);
    ay = fmaf(w, f01.y, ay);
    az = fmaf(w, f23.x, az);
    aw = fmaf(w, f23.y, aw);
}

__global__ __launch_bounds__(192) void agg_k(const __half* __restrict__ Hh,
                                             const int* __restrict__ offs,
                                             const int* __restrict__ es,
                                             const float* __restrict__ dinv,
                                             const float* __restrict__ b,
                                             float* __restrict__ OUT, int n, int do_relu) {
    int tid = threadIdx.x;
    int g = tid / 24, c4 = tid % 24;
    int node = blockIdx.x * 8 + g;
    if (node >= n) return;
    int e0 = offs[node], e1 = offs[node + 1];
    float di = dinv[node];
    float ax = 0.f, ay = 0.f, az = 0.f, aw = 0.f;
    int e = e0;
    for (; e + 1 < e1; e += 2) {
        int s0 = es[e], s1 = es[e + 1];
        float w0 = dinv[s0] * di;
        float w1 = dinv[s1] * di;
        uint2 r0 = *(const uint2*)&Hh[(size_t)s0 * CH + c4 * 4];
        uint2 r1 = *(const uint2*)&Hh[(size_t)s1 * CH + c4 * 4];
        acc_half4(r0.x, r0.y, w0, ax, ay, az, aw);
        acc_half4(r1.x, r1.y, w1, ax, ay, az, aw);
    }
    if (e < e1) {
        int s0 = es[e];
        float w0 = dinv[s0] * di;
        uint2 r0 = *(const uint2*)&Hh[(size_t)s0 * CH + c4 * 4];
        acc_half4(r0.x, r0.y, w0, ax, ay, az, aw);
    }
    // self-loop + bias
    uint2 rs = *(const uint2*)&Hh[(size_t)node * CH + c4 * 4];
    acc_half4(rs.x, rs.y, di * di, ax, ay, az, aw);
    float4 bv = *(const float4*)&b[c4 * 4];
    ax += bv.x; ay += bv.y; az += bv.z; aw += bv.w;
    if (do_relu) {
        ax = fmaxf(ax, 0.f);
        ay = fmaxf(ay, 0.f);
        az = fmaxf(az, 0.f);
        aw = fmaxf(aw, 0.f);
    }
    float4 o = {ax, ay, az, aw};
    *(float4*)&OUT[(size_t)node * CH + c4 * 4] = o;
}

// ---------------- launch ----------------

extern "C" void kernel_launch(void* const* d_in, const int* in_sizes, int n_in,
                              void* d_out, int out_size, void* d_ws, size_t ws_size,
                              hipStream_t stream) {
    const float* x = (const float*)d_in[0];
    const int* ei = (const int*)d_in[1];  // [2, E]: row0 = src, row1 = dst
    const float* W1 = (const float*)d_in[2];
    const float* b1 = (const float*)d_in[3];
    const float* W2 = (const float*)d_in[4];
    const float* b2 = (const float*)d_in[5];
    const float* W3 = (const float*)d_in[6];
    const float* b3 = (const float*)d_in[7];
    const float* W4 = (const float*)d_in[8];
    const float* b4 = (const float*)d_in[9];
    float* out = (float*)d_out;

    const int* src = ei;
    const int* dst = ei + NE;

    char* ws = (char*)d_ws;
    size_t o = 0;
    __half* Hh = (__half*)(ws + o);   o += al256((size_t)NN * CH * 2);
    float* F = (float*)(ws + o);      o += al256((size_t)NN * CH * 4);
    int* cnt = (int*)(ws + o);        o += al256((size_t)NN * 4);
    int* offs = (int*)(ws + o);       o += al256((size_t)(NN + 1) * 4);
    int* cursor = (int*)(ws + o);     o += al256((size_t)NN * 4);
    float* dinv = (float*)(ws + o);   o += al256((size_t)NN * 4);
    int* es = (int*)(ws + o);         o += al256((size_t)NE * 4);
    int* bsum = (int*)(ws + o);       o += al256(256 * 4);
    int* boff = (int*)(ws + o);       o += al256(256 * 4);

    const int NB_EDGE = (NE + 255) / 256;          // 3125
    const int NB_SCAN = (NN + 1 + 255) / 256;      // 196 (covers i<=N)
    const int NB_GEMM = (NN + 31) / 32;            // 1563
    const int NB_AGG = (NN + 7) / 8;               // 6250

    // graph preprocessing (once per launch)
    hipMemsetAsync(cnt, 0, (size_t)NN * 4, stream);
    count_deg_k<<<NB_EDGE, 256, 0, stream>>>(dst, cnt, NE);
    scan1_k<<<NB_SCAN, 256, 0, stream>>>(cnt, offs, bsum, NN);
    scan2_k<<<1, 256, 0, stream>>>(bsum, boff, NB_SCAN);
    scan3_k<<<NB_SCAN, 256, 0, stream>>>(offs, boff, cursor, dinv, cnt, NN);
    scatter_k<<<NB_EDGE, 256, 0, stream>>>(src, dst, cursor, es, NE);

    // layer 1: x(128) -> F(96)
    gemm_k<CIN0, 0><<<NB_GEMM, 192, 0, stream>>>(x, W1, Hh, NN);
    agg_k<<<NB_AGG, 192, 0, stream>>>(Hh, offs, es, dinv, b1, F, NN, 1);
    // layer 2: F -> F
    gemm_k<CH, 4><<<NB_GEMM, 192, 0, stream>>>(F, W2, Hh, NN);
    agg_k<<<NB_AGG, 192, 0, stream>>>(Hh, offs, es, dinv, b2, F, NN, 1);
    // layer 3
    gemm_k<CH, 4><<<NB_GEMM, 192, 0, stream>>>(F, W3, Hh, NN);
    agg_k<<<NB_AGG, 192, 0, stream>>>(Hh, offs, es, dinv, b3, F, NN, 1);
    // layer 4 (no relu) -> d_out
    gemm_k<CH, 4><<<NB_GEMM, 192, 0, stream>>>(F, W4, Hh, NN);
    agg_k<<<NB_AGG, 192, 0, stream>>>(Hh, offs, es, dinv, b4, out, NN, 0);
}